// Round 4
// baseline (662.434 us; speedup 1.0000x reference)
//
#include <hip/hip_runtime.h>
#include <hip/hip_fp16.h>

constexpr int N_ = 300;
constexpr int R_ = 48;
constexpr int B_ = 1048576;                        // 2^20
constexpr int NBXY = 38;                           // tiles of 8 texels, ceil(301/8)
constexpr int BINS_PP = NBXY * NBXY;               // 1444
constexpr int NBINS = 3 * BINS_PP;                 // 4332
constexpr int CAP = 1024;                          // slots per bin (mean 711)
constexpr int BPB = CAP * 6 / 256;                 // 24 blocks per bin
constexpr unsigned GATHER_BLOCKS = NBINS * BPB;    // 103968 = 8 * 12996
constexpr unsigned XCD_CHUNK = GATHER_BLOCKS / 8;  // 12996

// ws layout (bytes)
constexpr size_t OFF_MT   = 0;                     // fp16 texture (3,300,300,48) = 25,920,000
constexpr size_t OFF_VSUM = 25920000;              // 144 floats
constexpr size_t OFF_CNT  = 25920640;              // 4332 ints
constexpr size_t OFF_REC  = 25938048;              // 4332*1024 u32 = 17,743,872  (total ~43.7MB)

typedef float f32x4 __attribute__((ext_vector_type(4)));
union H8 { float4 f4; __half2 h2[4]; };

// --- init: zero bin counters + collapse line-sample analytically ---
// vector img (R,N,1), y=0, x=c: out = 0.5*(V[149]+V[150]) * (1 - |c|/2)
__global__ __launch_bounds__(256) void k_init(const float* __restrict__ vec,
                                              float* __restrict__ vsum,
                                              int* __restrict__ counts) {
    int t = blockIdx.x * 256 + threadIdx.x;
    if (t < NBINS) counts[t] = 0;
    if (t < 3 * R_) vsum[t] = 0.5f * (vec[t * N_ + 149] + vec[t * N_ + 150]);
}

// --- transpose matrices (3,R,N,N) f32 -> (3,N,N,R) fp16 ---
__global__ __launch_bounds__(256) void k_transpose(const float* __restrict__ mat,
                                                   __half2* __restrict__ mt2) {
    __shared__ float tile[R_][N_ + 1];
    int i = blockIdx.x / N_;
    int y = blockIdx.x - i * N_;
    const float* src = mat + ((size_t)i * R_ * N_ + y) * N_;
    for (int idx = threadIdx.x; idx < R_ * N_; idx += 256) {
        int r = idx / N_;
        int x = idx - r * N_;
        tile[r][x] = src[(size_t)r * N_ * N_ + x];
    }
    __syncthreads();
    __half2* dst = mt2 + (size_t)(i * N_ + y) * N_ * (R_ / 2);
    for (int idx = threadIdx.x; idx < N_ * (R_ / 2); idx += 256) {
        int x  = idx / (R_ / 2);
        int jj = idx - x * (R_ / 2);
        dst[idx] = __floats2half2_rn(tile[2 * jj][x], tile[2 * jj + 1][x]);
    }
}

// bilinear weights + clamped row offsets (in halfs) for one plane sample
struct BW { float w00, w01, w10, w11; int o00, o01, o10, o11; };
__device__ inline BW bilin(float xc, float yc) {
    float ix = (xc + 1.0f) * 150.0f - 0.5f;
    float iy = (yc + 1.0f) * 150.0f - 0.5f;
    float ix0f = floorf(ix), iy0f = floorf(iy);
    float wx = ix - ix0f, wy = iy - iy0f;
    int ix0 = (int)ix0f, iy0 = (int)iy0f;
    int ix1 = ix0 + 1, iy1 = iy0 + 1;
    BW r;
    r.w00 = (1.0f - wy) * (1.0f - wx);
    r.w01 = (1.0f - wy) * wx;
    r.w10 = wy * (1.0f - wx);
    r.w11 = wy * wx;
    bool bx0 = (unsigned)ix0 < (unsigned)N_;
    bool bx1 = (unsigned)ix1 < (unsigned)N_;
    bool by0 = (unsigned)iy0 < (unsigned)N_;
    bool by1 = (unsigned)iy1 < (unsigned)N_;
    if (!(bx0 && by0)) r.w00 = 0.0f;
    if (!(bx1 && by0)) r.w01 = 0.0f;
    if (!(bx0 && by1)) r.w10 = 0.0f;
    if (!(bx1 && by1)) r.w11 = 0.0f;
    int cx0 = min(max(ix0, 0), N_ - 1), cx1 = min(max(ix1, 0), N_ - 1);
    int cy0 = min(max(iy0, 0), N_ - 1), cy1 = min(max(iy1, 0), N_ - 1);
    r.o00 = (cy0 * N_ + cx0) * R_;
    r.o01 = (cy0 * N_ + cx1) * R_;
    r.o10 = (cy1 * N_ + cx0) * R_;
    r.o11 = (cy1 * N_ + cx1) * R_;
    return r;
}

// --- scatter: bin each (b,plane) sample by 8x8 texel tile ---
__global__ __launch_bounds__(256) void k_scatter(const float* __restrict__ coords,
                                                 int* __restrict__ counts,
                                                 unsigned* __restrict__ recs,
                                                 const __half* __restrict__ M,
                                                 const float* __restrict__ vsum,
                                                 float* __restrict__ out) {
    int s = blockIdx.x * 256 + threadIdx.x;        // [0, 3B)
    int plane = s >> 20;
    int b = s & (B_ - 1);
    float c0 = coords[3 * b], c1 = coords[3 * b + 1], c2 = coords[3 * b + 2];
    float xc, yc, cc;
    if (plane == 0)      { xc = c1; yc = c2; cc = c0; }
    else if (plane == 1) { xc = c2; yc = c0; cc = c1; }
    else                 { xc = c0; yc = c1; cc = c2; }
    float ix = (xc + 1.0f) * 150.0f - 0.5f;
    float iy = (yc + 1.0f) * 150.0f - 0.5f;
    int ix0 = (int)floorf(ix), iy0 = (int)floorf(iy);
    int bx = (ix0 + 1) >> 3, by = (iy0 + 1) >> 3;
    int bin = plane * BINS_PP + by * NBXY + bx;
    int pos = atomicAdd(&counts[bin], 1);
    if (pos < CAP) {
        recs[bin * CAP + pos] = (unsigned)b | ((unsigned)plane << 20);
    } else {
        // cold fallback: compute this sample's 48 channels directly (correctness net)
        BW w = bilin(xc, yc);
        float vw = 1.0f - 0.5f * fabsf(cc);
        const __half* Mi = M + (size_t)plane * N_ * N_ * R_;
        float* outp = out + (size_t)b * 144 + plane * 48;
        for (int j = 0; j < 6; ++j) {
            H8 u00, u01, u10, u11;
            u00.f4 = *reinterpret_cast<const float4*>(Mi + w.o00 + 8 * j);
            u01.f4 = *reinterpret_cast<const float4*>(Mi + w.o01 + 8 * j);
            u10.f4 = *reinterpret_cast<const float4*>(Mi + w.o10 + 8 * j);
            u11.f4 = *reinterpret_cast<const float4*>(Mi + w.o11 + 8 * j);
            for (int k = 0; k < 4; ++k) {
                float2 a00 = __half22float2(u00.h2[k]);
                float2 a01 = __half22float2(u01.h2[k]);
                float2 a10 = __half22float2(u10.h2[k]);
                float2 a11 = __half22float2(u11.h2[k]);
                float r0 = fmaf(a00.x, w.w00, fmaf(a01.x, w.w01, fmaf(a10.x, w.w10, a11.x * w.w11)));
                float r1 = fmaf(a00.y, w.w00, fmaf(a01.y, w.w01, fmaf(a10.y, w.w10, a11.y * w.w11)));
                outp[8 * j + 2 * k]     = r0 * (vsum[plane * R_ + 8 * j + 2 * k] * vw);
                outp[8 * j + 2 * k + 1] = r1 * (vsum[plane * R_ + 8 * j + 2 * k + 1] * vw);
            }
        }
    }
}

// --- gather: 24 blocks per bin; bin footprint 9x9 texels (~7.8KB) is L1-hot ---
__global__ __launch_bounds__(256) void k_gather(const float* __restrict__ coords,
                                                const int* __restrict__ counts,
                                                const unsigned* __restrict__ recs,
                                                const __half* __restrict__ M,
                                                const float* __restrict__ vsum,
                                                float* __restrict__ out) {
    unsigned bid  = blockIdx.x;
    unsigned vbid = (bid & 7) * XCD_CHUNK + (bid >> 3);   // contiguous bins per XCD
    unsigned bin  = vbid / BPB;
    unsigned lb   = vbid - bin * BPB;
    int cnt = counts[bin];
    if (cnt > CAP) cnt = CAP;
    unsigned g = lb * 256 + threadIdx.x;                  // [0, 6144)
    if (g >= (unsigned)(cnt * 6)) return;
    unsigned slot = g / 6;
    unsigned j = g - slot * 6;

    unsigned rec = recs[bin * CAP + slot];
    int b = rec & (B_ - 1);
    int plane = rec >> 20;

    float c0 = coords[3 * b], c1 = coords[3 * b + 1], c2 = coords[3 * b + 2];
    float xc, yc, cc;
    if (plane == 0)      { xc = c1; yc = c2; cc = c0; }
    else if (plane == 1) { xc = c2; yc = c0; cc = c1; }
    else                 { xc = c0; yc = c1; cc = c2; }

    BW w = bilin(xc, yc);
    const __half* Mi = M + (size_t)plane * N_ * N_ * R_;
    int co = 8 * j;

    H8 u00, u01, u10, u11;
    u00.f4 = *reinterpret_cast<const float4*>(Mi + w.o00 + co);
    u01.f4 = *reinterpret_cast<const float4*>(Mi + w.o01 + co);
    u10.f4 = *reinterpret_cast<const float4*>(Mi + w.o10 + co);
    u11.f4 = *reinterpret_cast<const float4*>(Mi + w.o11 + co);

    float vw = 1.0f - 0.5f * fabsf(cc);
    const float4* vs4 = reinterpret_cast<const float4*>(vsum + plane * R_ + co);
    float4 vv0 = vs4[0];
    float4 vv1 = vs4[1];

    float r[8];
#pragma unroll
    for (int k = 0; k < 4; ++k) {
        float2 a00 = __half22float2(u00.h2[k]);
        float2 a01 = __half22float2(u01.h2[k]);
        float2 a10 = __half22float2(u10.h2[k]);
        float2 a11 = __half22float2(u11.h2[k]);
        r[2 * k]     = fmaf(a00.x, w.w00, fmaf(a01.x, w.w01, fmaf(a10.x, w.w10, a11.x * w.w11)));
        r[2 * k + 1] = fmaf(a00.y, w.w00, fmaf(a01.y, w.w01, fmaf(a10.y, w.w10, a11.y * w.w11)));
    }

    f32x4 s0, s1;
    s0.x = r[0] * (vv0.x * vw); s0.y = r[1] * (vv0.y * vw);
    s0.z = r[2] * (vv0.z * vw); s0.w = r[3] * (vv0.w * vw);
    s1.x = r[4] * (vv1.x * vw); s1.y = r[5] * (vv1.y * vw);
    s1.z = r[6] * (vv1.z * vw); s1.w = r[7] * (vv1.w * vw);

    float* outp = out + (size_t)b * 144 + plane * 48 + co;
    __builtin_nontemporal_store(s0, reinterpret_cast<f32x4*>(outp));
    __builtin_nontemporal_store(s1, reinterpret_cast<f32x4*>(outp) + 1);
}

extern "C" void kernel_launch(void* const* d_in, const int* in_sizes, int n_in,
                              void* d_out, int out_size, void* d_ws, size_t ws_size,
                              hipStream_t stream) {
    const float* coords   = (const float*)d_in[0];
    const float* matrices = (const float*)d_in[1];
    const float* vectors  = (const float*)d_in[2];
    float* out = (float*)d_out;

    __half*   mt    = (__half*)((char*)d_ws + OFF_MT);
    float*    vsum  = (float*)((char*)d_ws + OFF_VSUM);
    int*      counts = (int*)((char*)d_ws + OFF_CNT);
    unsigned* recs  = (unsigned*)((char*)d_ws + OFF_REC);

    hipLaunchKernelGGL(k_init, dim3((NBINS + 255) / 256), dim3(256), 0, stream,
                       vectors, vsum, counts);
    hipLaunchKernelGGL(k_transpose, dim3(3 * N_), dim3(256), 0, stream,
                       matrices, (__half2*)mt);
    hipLaunchKernelGGL(k_scatter, dim3(3 * B_ / 256), dim3(256), 0, stream,
                       coords, counts, recs, mt, vsum, out);
    hipLaunchKernelGGL(k_gather, dim3(GATHER_BLOCKS), dim3(256), 0, stream,
                       coords, counts, recs, mt, vsum, out);
}

// Round 5
// 594.901 us; speedup vs baseline: 1.1135x; 1.1135x over previous
//
#include <hip/hip_runtime.h>
#include <hip/hip_fp16.h>

constexpr int N_ = 300;
constexpr int R_ = 48;
constexpr int B_ = 1048576;                        // 2^20
constexpr int NBXY = 38;                           // 8-texel tiles, ceil(301/8)
constexpr int BINS_PP = NBXY * NBXY;               // 1444
constexpr int NBINS = 3 * BINS_PP;                 // 4332
constexpr int SUBS = 8;                            // one sub-counter per XCD
constexpr int CAP_SUB = 126;                       // slots per (sub,bin); mean ~93
constexpr int SLOTS = SUBS * CAP_SUB;              // 1008 logical slots per bin
constexpr int BPB = 24;                            // blocks per bin (6144 thr >= 1008*6)
constexpr unsigned GATHER_BLOCKS = NBINS * BPB;    // 103968 = 8 * 12996
constexpr unsigned XCD_CHUNK = GATHER_BLOCKS / 8;  // 12996

// ws layout (bytes); total 43,524,736 <= 43.68MB proven in R4
constexpr size_t OFF_MT   = 0;                     // fp16 texture (3,300,300,48)
constexpr size_t OFF_VSUM = 25920000;
constexpr size_t OFF_CNT  = 25920640;              // int counts[SUBS][NBINS]
constexpr size_t OFF_REC  = 26059264;              // u32 recs[SUBS][NBINS][CAP_SUB]

typedef float f32x4 __attribute__((ext_vector_type(4)));
union H8 { float4 f4; __half2 h2[4]; };

// --- init: zero sub-counters + collapse line-sample analytically ---
// vector img (R,N,1), y=0, x=c: out = 0.5*(V[149]+V[150]) * (1 - |c|/2)
__global__ __launch_bounds__(256) void k_init(const float* __restrict__ vec,
                                              float* __restrict__ vsum,
                                              int* __restrict__ counts) {
    int t = blockIdx.x * 256 + threadIdx.x;
    if (t < SUBS * NBINS) counts[t] = 0;
    if (t < 3 * R_) vsum[t] = 0.5f * (vec[t * N_ + 149] + vec[t * N_ + 150]);
}

// --- transpose matrices (3,R,N,N) f32 -> (3,N,N,R) fp16 ---
__global__ __launch_bounds__(256) void k_transpose(const float* __restrict__ mat,
                                                   __half2* __restrict__ mt2) {
    __shared__ float tile[R_][N_ + 1];
    int i = blockIdx.x / N_;
    int y = blockIdx.x - i * N_;
    const float* src = mat + ((size_t)i * R_ * N_ + y) * N_;
    for (int idx = threadIdx.x; idx < R_ * N_; idx += 256) {
        int r = idx / N_;
        int x = idx - r * N_;
        tile[r][x] = src[(size_t)r * N_ * N_ + x];
    }
    __syncthreads();
    __half2* dst = mt2 + (size_t)(i * N_ + y) * N_ * (R_ / 2);
    for (int idx = threadIdx.x; idx < N_ * (R_ / 2); idx += 256) {
        int x  = idx / (R_ / 2);
        int jj = idx - x * (R_ / 2);
        dst[idx] = __floats2half2_rn(tile[2 * jj][x], tile[2 * jj + 1][x]);
    }
}

struct BW { float w00, w01, w10, w11; int o00, o01, o10, o11; };
__device__ inline BW bilin(float xc, float yc) {
    float ix = (xc + 1.0f) * 150.0f - 0.5f;
    float iy = (yc + 1.0f) * 150.0f - 0.5f;
    float ix0f = floorf(ix), iy0f = floorf(iy);
    float wx = ix - ix0f, wy = iy - iy0f;
    int ix0 = (int)ix0f, iy0 = (int)iy0f;
    int ix1 = ix0 + 1, iy1 = iy0 + 1;
    BW r;
    r.w00 = (1.0f - wy) * (1.0f - wx);
    r.w01 = (1.0f - wy) * wx;
    r.w10 = wy * (1.0f - wx);
    r.w11 = wy * wx;
    bool bx0 = (unsigned)ix0 < (unsigned)N_;
    bool bx1 = (unsigned)ix1 < (unsigned)N_;
    bool by0 = (unsigned)iy0 < (unsigned)N_;
    bool by1 = (unsigned)iy1 < (unsigned)N_;
    if (!(bx0 && by0)) r.w00 = 0.0f;
    if (!(bx1 && by0)) r.w01 = 0.0f;
    if (!(bx0 && by1)) r.w10 = 0.0f;
    if (!(bx1 && by1)) r.w11 = 0.0f;
    int cx0 = min(max(ix0, 0), N_ - 1), cx1 = min(max(ix1, 0), N_ - 1);
    int cy0 = min(max(iy0, 0), N_ - 1), cy1 = min(max(iy1, 0), N_ - 1);
    r.o00 = (cy0 * N_ + cx0) * R_;
    r.o01 = (cy0 * N_ + cx1) * R_;
    r.o10 = (cy1 * N_ + cx0) * R_;
    r.o11 = (cy1 * N_ + cx1) * R_;
    return r;
}

// --- scatter: bin each (b,plane) sample. Sub-counter per XCD kills the
// cross-XCD atomic ping-pong chain (R4: 630ns/op x 711 = 450us).
__global__ __launch_bounds__(256) void k_scatter(const float* __restrict__ coords,
                                                 int* __restrict__ counts,
                                                 unsigned* __restrict__ recs,
                                                 const __half* __restrict__ M,
                                                 const float* __restrict__ vsum,
                                                 float* __restrict__ out) {
    int s = blockIdx.x * 256 + threadIdx.x;        // [0, 3B)
    int plane = s >> 20;
    int b = s & (B_ - 1);
    int sub = blockIdx.x & 7;                      // = XCD under round-robin
    float c0 = coords[3 * b], c1 = coords[3 * b + 1], c2 = coords[3 * b + 2];
    float xc, yc, cc;
    if (plane == 0)      { xc = c1; yc = c2; cc = c0; }
    else if (plane == 1) { xc = c2; yc = c0; cc = c1; }
    else                 { xc = c0; yc = c1; cc = c2; }
    float ix = (xc + 1.0f) * 150.0f - 0.5f;
    float iy = (yc + 1.0f) * 150.0f - 0.5f;
    int ix0 = (int)floorf(ix), iy0 = (int)floorf(iy);
    int bx = (ix0 + 1) >> 3, by = (iy0 + 1) >> 3;
    int bin = plane * BINS_PP + by * NBXY + bx;
    int cell = sub * NBINS + bin;
    int pos = atomicAdd(&counts[cell], 1);
    if (pos < CAP_SUB) {
        recs[(size_t)cell * CAP_SUB + pos] = (unsigned)b | ((unsigned)plane << 20);
    } else {
        // rare overflow (~1e1 samples): compute directly (correctness net)
        BW w = bilin(xc, yc);
        float vw = 1.0f - 0.5f * fabsf(cc);
        const __half* Mi = M + (size_t)plane * N_ * N_ * R_;
        float* outp = out + (size_t)b * 144 + plane * 48;
        for (int j = 0; j < 6; ++j) {
            H8 u00, u01, u10, u11;
            u00.f4 = *reinterpret_cast<const float4*>(Mi + w.o00 + 8 * j);
            u01.f4 = *reinterpret_cast<const float4*>(Mi + w.o01 + 8 * j);
            u10.f4 = *reinterpret_cast<const float4*>(Mi + w.o10 + 8 * j);
            u11.f4 = *reinterpret_cast<const float4*>(Mi + w.o11 + 8 * j);
            for (int k = 0; k < 4; ++k) {
                float2 a00 = __half22float2(u00.h2[k]);
                float2 a01 = __half22float2(u01.h2[k]);
                float2 a10 = __half22float2(u10.h2[k]);
                float2 a11 = __half22float2(u11.h2[k]);
                float r0 = fmaf(a00.x, w.w00, fmaf(a01.x, w.w01, fmaf(a10.x, w.w10, a11.x * w.w11)));
                float r1 = fmaf(a00.y, w.w00, fmaf(a01.y, w.w01, fmaf(a10.y, w.w10, a11.y * w.w11)));
                outp[8 * j + 2 * k]     = r0 * (vsum[plane * R_ + 8 * j + 2 * k] * vw);
                outp[8 * j + 2 * k + 1] = r1 * (vsum[plane * R_ + 8 * j + 2 * k + 1] * vw);
            }
        }
    }
}

// --- gather: 24 blocks per bin; bin texture footprint 9x9 texels (~7.8KB)
// is L1-hot; each XCD owns a contiguous bin chunk (~3.2MB texture < 4MB L2).
__global__ __launch_bounds__(256) void k_gather(const float* __restrict__ coords,
                                                const int* __restrict__ counts,
                                                const unsigned* __restrict__ recs,
                                                const __half* __restrict__ M,
                                                const float* __restrict__ vsum,
                                                float* __restrict__ out) {
    unsigned bid  = blockIdx.x;
    unsigned vbid = (bid & 7) * XCD_CHUNK + (bid >> 3);   // contiguous bins per XCD
    unsigned bin  = vbid / BPB;
    unsigned lb   = vbid - bin * BPB;
    unsigned g = lb * 256 + threadIdx.x;                  // [0, 6144)
    unsigned slot = g / 6;                                // [0, 1024)
    unsigned j = g - slot * 6;
    if (slot >= (unsigned)SLOTS) return;
    unsigned sub = slot / CAP_SUB;
    unsigned idx = slot - sub * CAP_SUB;
    unsigned cell = sub * NBINS + bin;
    int cnt = min(counts[cell], CAP_SUB);
    if ((int)idx >= cnt) return;

    unsigned rec = __builtin_nontemporal_load(recs + (size_t)cell * CAP_SUB + idx);
    int b = rec & (B_ - 1);
    int plane = rec >> 20;

    float c0 = __builtin_nontemporal_load(coords + 3 * b);
    float c1 = __builtin_nontemporal_load(coords + 3 * b + 1);
    float c2 = __builtin_nontemporal_load(coords + 3 * b + 2);
    float xc, yc, cc;
    if (plane == 0)      { xc = c1; yc = c2; cc = c0; }
    else if (plane == 1) { xc = c2; yc = c0; cc = c1; }
    else                 { xc = c0; yc = c1; cc = c2; }

    BW w = bilin(xc, yc);
    const __half* Mi = M + (size_t)plane * N_ * N_ * R_;
    int co = 8 * j;

    H8 u00, u01, u10, u11;
    u00.f4 = *reinterpret_cast<const float4*>(Mi + w.o00 + co);
    u01.f4 = *reinterpret_cast<const float4*>(Mi + w.o01 + co);
    u10.f4 = *reinterpret_cast<const float4*>(Mi + w.o10 + co);
    u11.f4 = *reinterpret_cast<const float4*>(Mi + w.o11 + co);

    float vw = 1.0f - 0.5f * fabsf(cc);
    const float4* vs4 = reinterpret_cast<const float4*>(vsum + plane * R_ + co);
    float4 vv0 = vs4[0];
    float4 vv1 = vs4[1];

    float r[8];
#pragma unroll
    for (int k = 0; k < 4; ++k) {
        float2 a00 = __half22float2(u00.h2[k]);
        float2 a01 = __half22float2(u01.h2[k]);
        float2 a10 = __half22float2(u10.h2[k]);
        float2 a11 = __half22float2(u11.h2[k]);
        r[2 * k]     = fmaf(a00.x, w.w00, fmaf(a01.x, w.w01, fmaf(a10.x, w.w10, a11.x * w.w11)));
        r[2 * k + 1] = fmaf(a00.y, w.w00, fmaf(a01.y, w.w01, fmaf(a10.y, w.w10, a11.y * w.w11)));
    }

    f32x4 s0, s1;
    s0.x = r[0] * (vv0.x * vw); s0.y = r[1] * (vv0.y * vw);
    s0.z = r[2] * (vv0.z * vw); s0.w = r[3] * (vv0.w * vw);
    s1.x = r[4] * (vv1.x * vw); s1.y = r[5] * (vv1.y * vw);
    s1.z = r[6] * (vv1.z * vw); s1.w = r[7] * (vv1.w * vw);

    float* outp = out + (size_t)b * 144 + plane * 48 + co;
    __builtin_nontemporal_store(s0, reinterpret_cast<f32x4*>(outp));
    __builtin_nontemporal_store(s1, reinterpret_cast<f32x4*>(outp) + 1);
}

extern "C" void kernel_launch(void* const* d_in, const int* in_sizes, int n_in,
                              void* d_out, int out_size, void* d_ws, size_t ws_size,
                              hipStream_t stream) {
    const float* coords   = (const float*)d_in[0];
    const float* matrices = (const float*)d_in[1];
    const float* vectors  = (const float*)d_in[2];
    float* out = (float*)d_out;

    __half*   mt     = (__half*)((char*)d_ws + OFF_MT);
    float*    vsum   = (float*)((char*)d_ws + OFF_VSUM);
    int*      counts = (int*)((char*)d_ws + OFF_CNT);
    unsigned* recs   = (unsigned*)((char*)d_ws + OFF_REC);

    hipLaunchKernelGGL(k_init, dim3((SUBS * NBINS + 255) / 256), dim3(256), 0, stream,
                       vectors, vsum, counts);
    hipLaunchKernelGGL(k_transpose, dim3(3 * N_), dim3(256), 0, stream,
                       matrices, (__half2*)mt);
    hipLaunchKernelGGL(k_scatter, dim3(3 * B_ / 256), dim3(256), 0, stream,
                       coords, counts, recs, mt, vsum, out);
    hipLaunchKernelGGL(k_gather, dim3(GATHER_BLOCKS), dim3(256), 0, stream,
                       coords, counts, recs, mt, vsum, out);
}

// Round 6
// 433.417 us; speedup vs baseline: 1.5284x; 1.3726x over previous
//
#include <hip/hip_runtime.h>
#include <hip/hip_fp16.h>

constexpr int N_ = 300;
constexpr int R_ = 48;
constexpr int B_ = 1048576;                        // 2^20
constexpr int NBXY = 38;                           // 8-texel tiles, ceil(301/8)
constexpr int BINS_PP = NBXY * NBXY;               // 1444
constexpr int NBINS = 3 * BINS_PP;                 // 4332
constexpr int SUBS = 16;                           // sub-counters: spread atomic lines
constexpr int CAP_SUB = 61;                        // slots per (sub,bin); mean 44.4
constexpr int SLOTS = SUBS * CAP_SUB;              // 976 logical slots per bin
constexpr int BPB = 24;                            // blocks per bin (6144 thr >= 976*6)
constexpr unsigned GATHER_BLOCKS = NBINS * BPB;    // 103968 = 8 * 12996
constexpr unsigned XCD_CHUNK = GATHER_BLOCKS / 8;  // 12996

// ws layout (bytes); total 43,387,264 < 43.66MB proven in R4
constexpr size_t OFF_MT   = 0;                     // fp16 texture (3,300,300,48) = 25,920,000
constexpr size_t OFF_VSUM = 25920000;              // 144 floats
constexpr size_t OFF_CNT  = 25920640;              // int counts[SUBS*NBINS][2] (8B-padded cells)
constexpr size_t OFF_REC  = 26475136;              // u32 recs[SUBS][NBINS][CAP_SUB]

typedef float f32x4 __attribute__((ext_vector_type(4)));
union H8 { float4 f4; __half2 h2[4]; };

// --- init: zero padded counters + collapse line-sample analytically ---
// vector img (R,N,1), y=0, x=c: out = 0.5*(V[149]+V[150]) * (1 - |c|/2)
__global__ __launch_bounds__(256) void k_init(const float* __restrict__ vec,
                                              float* __restrict__ vsum,
                                              int* __restrict__ counts) {
    int t = blockIdx.x * 256 + threadIdx.x;
    if (t < 2 * SUBS * NBINS) counts[t] = 0;
    if (t < 3 * R_) vsum[t] = 0.5f * (vec[t * N_ + 149] + vec[t * N_ + 150]);
}

// --- transpose matrices (3,R,N,N) f32 -> (3,N,N,R) fp16 ---
__global__ __launch_bounds__(256) void k_transpose(const float* __restrict__ mat,
                                                   __half2* __restrict__ mt2) {
    __shared__ float tile[R_][N_ + 1];
    int i = blockIdx.x / N_;
    int y = blockIdx.x - i * N_;
    const float* src = mat + ((size_t)i * R_ * N_ + y) * N_;
    for (int idx = threadIdx.x; idx < R_ * N_; idx += 256) {
        int r = idx / N_;
        int x = idx - r * N_;
        tile[r][x] = src[(size_t)r * N_ * N_ + x];
    }
    __syncthreads();
    __half2* dst = mt2 + (size_t)(i * N_ + y) * N_ * (R_ / 2);
    for (int idx = threadIdx.x; idx < N_ * (R_ / 2); idx += 256) {
        int x  = idx / (R_ / 2);
        int jj = idx - x * (R_ / 2);
        dst[idx] = __floats2half2_rn(tile[2 * jj][x], tile[2 * jj + 1][x]);
    }
}

struct BW { float w00, w01, w10, w11; int o00, o01, o10, o11; };
__device__ inline BW bilin(float xc, float yc) {
    float ix = (xc + 1.0f) * 150.0f - 0.5f;
    float iy = (yc + 1.0f) * 150.0f - 0.5f;
    float ix0f = floorf(ix), iy0f = floorf(iy);
    float wx = ix - ix0f, wy = iy - iy0f;
    int ix0 = (int)ix0f, iy0 = (int)iy0f;
    int ix1 = ix0 + 1, iy1 = iy0 + 1;
    BW r;
    r.w00 = (1.0f - wy) * (1.0f - wx);
    r.w01 = (1.0f - wy) * wx;
    r.w10 = wy * (1.0f - wx);
    r.w11 = wy * wx;
    bool bx0 = (unsigned)ix0 < (unsigned)N_;
    bool bx1 = (unsigned)ix1 < (unsigned)N_;
    bool by0 = (unsigned)iy0 < (unsigned)N_;
    bool by1 = (unsigned)iy1 < (unsigned)N_;
    if (!(bx0 && by0)) r.w00 = 0.0f;
    if (!(bx1 && by0)) r.w01 = 0.0f;
    if (!(bx0 && by1)) r.w10 = 0.0f;
    if (!(bx1 && by1)) r.w11 = 0.0f;
    int cx0 = min(max(ix0, 0), N_ - 1), cx1 = min(max(ix1, 0), N_ - 1);
    int cy0 = min(max(iy0, 0), N_ - 1), cy1 = min(max(iy1, 0), N_ - 1);
    r.o00 = (cy0 * N_ + cx0) * R_;
    r.o01 = (cy0 * N_ + cx1) * R_;
    r.o10 = (cy1 * N_ + cx0) * R_;
    r.o11 = (cy1 * N_ + cx1) * R_;
    return r;
}

// --- scatter: bin each (b,plane) sample by 8x8 texel tile.
// Atomics serialize per 128B LINE at the cache: 16 subs x 8B-padded cells
// spread 3.14M atomics over 4332 lines (~720 ops/line ~= 25us).
__global__ __launch_bounds__(256) void k_scatter(const float* __restrict__ coords,
                                                 int* __restrict__ counts,
                                                 unsigned* __restrict__ recs,
                                                 const __half* __restrict__ M,
                                                 const float* __restrict__ vsum,
                                                 float* __restrict__ out) {
    int s = blockIdx.x * 256 + threadIdx.x;        // [0, 3B)
    int plane = s >> 20;
    int b = s & (B_ - 1);
    int sub = blockIdx.x & (SUBS - 1);
    float c0 = coords[3 * b], c1 = coords[3 * b + 1], c2 = coords[3 * b + 2];
    float xc, yc, cc;
    if (plane == 0)      { xc = c1; yc = c2; cc = c0; }
    else if (plane == 1) { xc = c2; yc = c0; cc = c1; }
    else                 { xc = c0; yc = c1; cc = c2; }
    float ix = (xc + 1.0f) * 150.0f - 0.5f;
    float iy = (yc + 1.0f) * 150.0f - 0.5f;
    int ix0 = (int)floorf(ix), iy0 = (int)floorf(iy);
    int bx = (ix0 + 1) >> 3, by = (iy0 + 1) >> 3;
    int bin = plane * BINS_PP + by * NBXY + bx;
    int cell = sub * NBINS + bin;
    int pos = atomicAdd(&counts[2 * cell], 1);     // 8B-padded cell
    if (pos < CAP_SUB) {
        recs[(size_t)cell * CAP_SUB + pos] = (unsigned)b | ((unsigned)plane << 20);
    } else {
        // rare overflow (~1e3 samples): compute directly (correctness net)
        BW w = bilin(xc, yc);
        float vw = 1.0f - 0.5f * fabsf(cc);
        const __half* Mi = M + (size_t)plane * N_ * N_ * R_;
        float* outp = out + (size_t)b * 144 + plane * 48;
        for (int j = 0; j < 6; ++j) {
            H8 u00, u01, u10, u11;
            u00.f4 = *reinterpret_cast<const float4*>(Mi + w.o00 + 8 * j);
            u01.f4 = *reinterpret_cast<const float4*>(Mi + w.o01 + 8 * j);
            u10.f4 = *reinterpret_cast<const float4*>(Mi + w.o10 + 8 * j);
            u11.f4 = *reinterpret_cast<const float4*>(Mi + w.o11 + 8 * j);
            for (int k = 0; k < 4; ++k) {
                float2 a00 = __half22float2(u00.h2[k]);
                float2 a01 = __half22float2(u01.h2[k]);
                float2 a10 = __half22float2(u10.h2[k]);
                float2 a11 = __half22float2(u11.h2[k]);
                float r0 = fmaf(a00.x, w.w00, fmaf(a01.x, w.w01, fmaf(a10.x, w.w10, a11.x * w.w11)));
                float r1 = fmaf(a00.y, w.w00, fmaf(a01.y, w.w01, fmaf(a10.y, w.w10, a11.y * w.w11)));
                outp[8 * j + 2 * k]     = r0 * (vsum[plane * R_ + 8 * j + 2 * k] * vw);
                outp[8 * j + 2 * k + 1] = r1 * (vsum[plane * R_ + 8 * j + 2 * k + 1] * vw);
            }
        }
    }
}

// --- gather: 24 blocks per bin; bin texture footprint 9x9 texels (~7.8KB)
// is L1-hot; each XCD owns a contiguous bin chunk (~3.2MB texture < 4MB L2).
// Plain cached loads (NT loads were a 2.5x regression in R5).
__global__ __launch_bounds__(256) void k_gather(const float* __restrict__ coords,
                                                const int* __restrict__ counts,
                                                const unsigned* __restrict__ recs,
                                                const __half* __restrict__ M,
                                                const float* __restrict__ vsum,
                                                float* __restrict__ out) {
    unsigned bid  = blockIdx.x;
    unsigned vbid = (bid & 7) * XCD_CHUNK + (bid >> 3);   // contiguous bins per XCD
    unsigned bin  = vbid / BPB;
    unsigned lb   = vbid - bin * BPB;
    unsigned g = lb * 256 + threadIdx.x;                  // [0, 6144)
    unsigned slot = g / 6;                                // [0, 1024)
    unsigned j = g - slot * 6;
    if (slot >= (unsigned)SLOTS) return;
    unsigned sub = slot / CAP_SUB;
    unsigned idx = slot - sub * CAP_SUB;
    unsigned cell = sub * NBINS + bin;
    int cnt = min(counts[2 * cell], CAP_SUB);
    if ((int)idx >= cnt) return;

    unsigned rec = recs[(size_t)cell * CAP_SUB + idx];
    int b = rec & (B_ - 1);
    int plane = rec >> 20;

    float c0 = coords[3 * b], c1 = coords[3 * b + 1], c2 = coords[3 * b + 2];
    float xc, yc, cc;
    if (plane == 0)      { xc = c1; yc = c2; cc = c0; }
    else if (plane == 1) { xc = c2; yc = c0; cc = c1; }
    else                 { xc = c0; yc = c1; cc = c2; }

    BW w = bilin(xc, yc);
    const __half* Mi = M + (size_t)plane * N_ * N_ * R_;
    int co = 8 * j;

    H8 u00, u01, u10, u11;
    u00.f4 = *reinterpret_cast<const float4*>(Mi + w.o00 + co);
    u01.f4 = *reinterpret_cast<const float4*>(Mi + w.o01 + co);
    u10.f4 = *reinterpret_cast<const float4*>(Mi + w.o10 + co);
    u11.f4 = *reinterpret_cast<const float4*>(Mi + w.o11 + co);

    float vw = 1.0f - 0.5f * fabsf(cc);
    const float4* vs4 = reinterpret_cast<const float4*>(vsum + plane * R_ + co);
    float4 vv0 = vs4[0];
    float4 vv1 = vs4[1];

    float r[8];
#pragma unroll
    for (int k = 0; k < 4; ++k) {
        float2 a00 = __half22float2(u00.h2[k]);
        float2 a01 = __half22float2(u01.h2[k]);
        float2 a10 = __half22float2(u10.h2[k]);
        float2 a11 = __half22float2(u11.h2[k]);
        r[2 * k]     = fmaf(a00.x, w.w00, fmaf(a01.x, w.w01, fmaf(a10.x, w.w10, a11.x * w.w11)));
        r[2 * k + 1] = fmaf(a00.y, w.w00, fmaf(a01.y, w.w01, fmaf(a10.y, w.w10, a11.y * w.w11)));
    }

    f32x4 s0, s1;
    s0.x = r[0] * (vv0.x * vw); s0.y = r[1] * (vv0.y * vw);
    s0.z = r[2] * (vv0.z * vw); s0.w = r[3] * (vv0.w * vw);
    s1.x = r[4] * (vv1.x * vw); s1.y = r[5] * (vv1.y * vw);
    s1.z = r[6] * (vv1.z * vw); s1.w = r[7] * (vv1.w * vw);

    float* outp = out + (size_t)b * 144 + plane * 48 + co;
    __builtin_nontemporal_store(s0, reinterpret_cast<f32x4*>(outp));
    __builtin_nontemporal_store(s1, reinterpret_cast<f32x4*>(outp) + 1);
}

extern "C" void kernel_launch(void* const* d_in, const int* in_sizes, int n_in,
                              void* d_out, int out_size, void* d_ws, size_t ws_size,
                              hipStream_t stream) {
    const float* coords   = (const float*)d_in[0];
    const float* matrices = (const float*)d_in[1];
    const float* vectors  = (const float*)d_in[2];
    float* out = (float*)d_out;

    __half*   mt     = (__half*)((char*)d_ws + OFF_MT);
    float*    vsum   = (float*)((char*)d_ws + OFF_VSUM);
    int*      counts = (int*)((char*)d_ws + OFF_CNT);
    unsigned* recs   = (unsigned*)((char*)d_ws + OFF_REC);

    hipLaunchKernelGGL(k_init, dim3((2 * SUBS * NBINS + 255) / 256), dim3(256), 0, stream,
                       vectors, vsum, counts);
    hipLaunchKernelGGL(k_transpose, dim3(3 * N_), dim3(256), 0, stream,
                       matrices, (__half2*)mt);
    hipLaunchKernelGGL(k_scatter, dim3(3 * B_ / 256), dim3(256), 0, stream,
                       coords, counts, recs, mt, vsum, out);
    hipLaunchKernelGGL(k_gather, dim3(GATHER_BLOCKS), dim3(256), 0, stream,
                       coords, counts, recs, mt, vsum, out);
}

// Round 7
// 367.695 us; speedup vs baseline: 1.8016x; 1.1787x over previous
//
#include <hip/hip_runtime.h>
#include <hip/hip_fp16.h>

constexpr int N_ = 300;
constexpr int R_ = 48;
constexpr int B_ = 1048576;                        // 2^20
constexpr int NBXY = 38;                           // 8-texel tiles, ceil(301/8)
constexpr int BINS_PP = NBXY * NBXY;               // 1444
constexpr int NBINS = 3 * BINS_PP;                 // 4332
constexpr int SUBS = 8;                            // one sub per XCD (blockIdx&7)
constexpr int CAP_SUB = 112;                       // mean 90.6, +2.3 sigma
constexpr int CNT_STRIDE = 16;                     // ints; 64B-padded counter cells
constexpr int SLOTS = SUBS * CAP_SUB;              // 896 slots per bin
constexpr int BPB = 21;                            // 5376 threads >= 896*6
constexpr unsigned NWORK = NBINS * BPB;            // 90,972
constexpr unsigned GATHER_BLOCKS = 90976;          // pad to 8*11372
constexpr unsigned XCD_CHUNK = GATHER_BLOCKS / 8;  // 11372

// ws layout (bytes); end 43,664,512 < 43,681,920 proven in R4
constexpr size_t OFF_MT   = 0;                     // fp16 texture (3,300,300,48)
constexpr size_t OFF_VSUM = 25920000;              // 144 floats (+pad)
constexpr size_t OFF_CNT  = 25920640;              // int counts[SUBS*NBINS][16] 64B cells
constexpr size_t OFF_REC  = 28138624;              // u32 recs[SUBS*NBINS][CAP_SUB]

typedef float f32x4 __attribute__((ext_vector_type(4)));
union H8 { float4 f4; __half2 h2[4]; };

// --- init: zero padded counters + collapse line-sample analytically ---
// vector img (R,N,1), y=0, x=c: out = 0.5*(V[149]+V[150]) * (1 - |c|/2)
__global__ __launch_bounds__(256) void k_init(const float* __restrict__ vec,
                                              float* __restrict__ vsum,
                                              int* __restrict__ counts) {
    int t = blockIdx.x * 256 + threadIdx.x;
    if (t < CNT_STRIDE * SUBS * NBINS) counts[t] = 0;
    if (t < 3 * R_) vsum[t] = 0.5f * (vec[t * N_ + 149] + vec[t * N_ + 150]);
}

// --- transpose matrices (3,R,N,N) f32 -> (3,N,N,R) fp16 ---
__global__ __launch_bounds__(256) void k_transpose(const float* __restrict__ mat,
                                                   __half2* __restrict__ mt2) {
    __shared__ float tile[R_][N_ + 1];
    int i = blockIdx.x / N_;
    int y = blockIdx.x - i * N_;
    const float* src = mat + ((size_t)i * R_ * N_ + y) * N_;
    for (int idx = threadIdx.x; idx < R_ * N_; idx += 256) {
        int r = idx / N_;
        int x = idx - r * N_;
        tile[r][x] = src[(size_t)r * N_ * N_ + x];
    }
    __syncthreads();
    __half2* dst = mt2 + (size_t)(i * N_ + y) * N_ * (R_ / 2);
    for (int idx = threadIdx.x; idx < N_ * (R_ / 2); idx += 256) {
        int x  = idx / (R_ / 2);
        int jj = idx - x * (R_ / 2);
        dst[idx] = __floats2half2_rn(tile[2 * jj][x], tile[2 * jj + 1][x]);
    }
}

struct BW { float w00, w01, w10, w11; int o00, o01, o10, o11; };
__device__ inline BW bilin(float xc, float yc) {
    float ix = (xc + 1.0f) * 150.0f - 0.5f;
    float iy = (yc + 1.0f) * 150.0f - 0.5f;
    float ix0f = floorf(ix), iy0f = floorf(iy);
    float wx = ix - ix0f, wy = iy - iy0f;
    int ix0 = (int)ix0f, iy0 = (int)iy0f;
    int ix1 = ix0 + 1, iy1 = iy0 + 1;
    BW r;
    r.w00 = (1.0f - wy) * (1.0f - wx);
    r.w01 = (1.0f - wy) * wx;
    r.w10 = wy * (1.0f - wx);
    r.w11 = wy * wx;
    bool bx0 = (unsigned)ix0 < (unsigned)N_;
    bool bx1 = (unsigned)ix1 < (unsigned)N_;
    bool by0 = (unsigned)iy0 < (unsigned)N_;
    bool by1 = (unsigned)iy1 < (unsigned)N_;
    if (!(bx0 && by0)) r.w00 = 0.0f;
    if (!(bx1 && by0)) r.w01 = 0.0f;
    if (!(bx0 && by1)) r.w10 = 0.0f;
    if (!(bx1 && by1)) r.w11 = 0.0f;
    int cx0 = min(max(ix0, 0), N_ - 1), cx1 = min(max(ix1, 0), N_ - 1);
    int cy0 = min(max(iy0, 0), N_ - 1), cy1 = min(max(iy1, 0), N_ - 1);
    r.o00 = (cy0 * N_ + cx0) * R_;
    r.o01 = (cy0 * N_ + cx1) * R_;
    r.o10 = (cy1 * N_ + cx0) * R_;
    r.o11 = (cy1 * N_ + cx1) * R_;
    return r;
}

__device__ inline void direct_sample(float xc, float yc, float cc, int plane, int b,
                                     const __half* __restrict__ M,
                                     const float* __restrict__ vsum,
                                     float* __restrict__ out) {
    BW w = bilin(xc, yc);
    float vw = 1.0f - 0.5f * fabsf(cc);
    const __half* Mi = M + (size_t)plane * N_ * N_ * R_;
    float* outp = out + (size_t)b * 144 + plane * 48;
    for (int j = 0; j < 6; ++j) {
        H8 u00, u01, u10, u11;
        u00.f4 = *reinterpret_cast<const float4*>(Mi + w.o00 + 8 * j);
        u01.f4 = *reinterpret_cast<const float4*>(Mi + w.o01 + 8 * j);
        u10.f4 = *reinterpret_cast<const float4*>(Mi + w.o10 + 8 * j);
        u11.f4 = *reinterpret_cast<const float4*>(Mi + w.o11 + 8 * j);
        for (int k = 0; k < 4; ++k) {
            float2 a00 = __half22float2(u00.h2[k]);
            float2 a01 = __half22float2(u01.h2[k]);
            float2 a10 = __half22float2(u10.h2[k]);
            float2 a11 = __half22float2(u11.h2[k]);
            float r0 = fmaf(a00.x, w.w00, fmaf(a01.x, w.w01, fmaf(a10.x, w.w10, a11.x * w.w11)));
            float r1 = fmaf(a00.y, w.w00, fmaf(a01.y, w.w01, fmaf(a10.y, w.w10, a11.y * w.w11)));
            out[(size_t)b * 144 + plane * 48 + 8 * j + 2 * k]     = r0 * (vsum[plane * R_ + 8 * j + 2 * k] * vw);
            out[(size_t)b * 144 + plane * 48 + 8 * j + 2 * k + 1] = r1 * (vsum[plane * R_ + 8 * j + 2 * k + 1] * vw);
        }
        (void)outp;
    }
}

// --- scatter: one thread per b, 3 plane-records. Counter cells are 64B-padded
// and sub=blockIdx&7 keeps every counter LINE private to one XCD:
// 181 ops/line x ~39ns = ~7us of atomic serialization (R4 calibration).
__global__ __launch_bounds__(256) void k_scatter(const float* __restrict__ coords,
                                                 int* __restrict__ counts,
                                                 unsigned* __restrict__ recs,
                                                 const __half* __restrict__ M,
                                                 const float* __restrict__ vsum,
                                                 float* __restrict__ out) {
    int b = blockIdx.x * 256 + threadIdx.x;        // [0, B)
    int sub = blockIdx.x & 7;                      // = XCD under round-robin
    float c0 = coords[3 * b], c1 = coords[3 * b + 1], c2 = coords[3 * b + 2];
#pragma unroll
    for (int plane = 0; plane < 3; ++plane) {
        float xc, yc, cc;
        if (plane == 0)      { xc = c1; yc = c2; cc = c0; }
        else if (plane == 1) { xc = c2; yc = c0; cc = c1; }
        else                 { xc = c0; yc = c1; cc = c2; }
        float ix = (xc + 1.0f) * 150.0f - 0.5f;
        float iy = (yc + 1.0f) * 150.0f - 0.5f;
        int ix0 = (int)floorf(ix), iy0 = (int)floorf(iy);
        int bx = (ix0 + 1) >> 3, by = (iy0 + 1) >> 3;
        int bin = plane * BINS_PP + by * NBXY + bx;
        int cell = sub * NBINS + bin;
        int pos = atomicAdd(&counts[cell * CNT_STRIDE], 1);
        if (pos < CAP_SUB) {
            recs[(size_t)cell * CAP_SUB + pos] = (unsigned)b;
        } else {
            direct_sample(xc, yc, cc, plane, b, M, vsum, out);  // rare (~1.6k)
        }
    }
}

// --- gather: 21 blocks per bin; bin texture footprint 9x9 texels (~7.8KB)
// is L1-hot; each XCD owns a contiguous bin chunk (~3.3MB texture < 4MB L2).
__global__ __launch_bounds__(256) void k_gather(const float* __restrict__ coords,
                                                const int* __restrict__ counts,
                                                const unsigned* __restrict__ recs,
                                                const __half* __restrict__ M,
                                                const float* __restrict__ vsum,
                                                float* __restrict__ out) {
    unsigned bid  = blockIdx.x;
    unsigned vbid = (bid & 7) * XCD_CHUNK + (bid >> 3);   // contiguous bins per XCD
    if (vbid >= NWORK) return;
    unsigned bin  = vbid / BPB;
    unsigned lb   = vbid - bin * BPB;
    unsigned g = lb * 256 + threadIdx.x;                  // [0, 5376)
    unsigned slot = g / 6;                                // [0, 896)
    unsigned j = g - slot * 6;
    unsigned sub = slot / CAP_SUB;
    unsigned idx = slot - sub * CAP_SUB;
    unsigned cell = sub * NBINS + bin;
    int cnt = min(counts[cell * CNT_STRIDE], CAP_SUB);
    if ((int)idx >= cnt) return;

    int b = (int)recs[(size_t)cell * CAP_SUB + idx];
    int plane = bin / BINS_PP;

    float c0 = coords[3 * b], c1 = coords[3 * b + 1], c2 = coords[3 * b + 2];
    float xc, yc, cc;
    if (plane == 0)      { xc = c1; yc = c2; cc = c0; }
    else if (plane == 1) { xc = c2; yc = c0; cc = c1; }
    else                 { xc = c0; yc = c1; cc = c2; }

    BW w = bilin(xc, yc);
    const __half* Mi = M + (size_t)plane * N_ * N_ * R_;
    int co = 8 * j;

    H8 u00, u01, u10, u11;
    u00.f4 = *reinterpret_cast<const float4*>(Mi + w.o00 + co);
    u01.f4 = *reinterpret_cast<const float4*>(Mi + w.o01 + co);
    u10.f4 = *reinterpret_cast<const float4*>(Mi + w.o10 + co);
    u11.f4 = *reinterpret_cast<const float4*>(Mi + w.o11 + co);

    float vw = 1.0f - 0.5f * fabsf(cc);
    const float4* vs4 = reinterpret_cast<const float4*>(vsum + plane * R_ + co);
    float4 vv0 = vs4[0];
    float4 vv1 = vs4[1];

    float r[8];
#pragma unroll
    for (int k = 0; k < 4; ++k) {
        float2 a00 = __half22float2(u00.h2[k]);
        float2 a01 = __half22float2(u01.h2[k]);
        float2 a10 = __half22float2(u10.h2[k]);
        float2 a11 = __half22float2(u11.h2[k]);
        r[2 * k]     = fmaf(a00.x, w.w00, fmaf(a01.x, w.w01, fmaf(a10.x, w.w10, a11.x * w.w11)));
        r[2 * k + 1] = fmaf(a00.y, w.w00, fmaf(a01.y, w.w01, fmaf(a10.y, w.w10, a11.y * w.w11)));
    }

    f32x4 s0, s1;
    s0.x = r[0] * (vv0.x * vw); s0.y = r[1] * (vv0.y * vw);
    s0.z = r[2] * (vv0.z * vw); s0.w = r[3] * (vv0.w * vw);
    s1.x = r[4] * (vv1.x * vw); s1.y = r[5] * (vv1.y * vw);
    s1.z = r[6] * (vv1.z * vw); s1.w = r[7] * (vv1.w * vw);

    float* outp = out + (size_t)b * 144 + plane * 48 + co;
    __builtin_nontemporal_store(s0, reinterpret_cast<f32x4*>(outp));
    __builtin_nontemporal_store(s1, reinterpret_cast<f32x4*>(outp) + 1);
}

extern "C" void kernel_launch(void* const* d_in, const int* in_sizes, int n_in,
                              void* d_out, int out_size, void* d_ws, size_t ws_size,
                              hipStream_t stream) {
    const float* coords   = (const float*)d_in[0];
    const float* matrices = (const float*)d_in[1];
    const float* vectors  = (const float*)d_in[2];
    float* out = (float*)d_out;

    __half*   mt     = (__half*)((char*)d_ws + OFF_MT);
    float*    vsum   = (float*)((char*)d_ws + OFF_VSUM);
    int*      counts = (int*)((char*)d_ws + OFF_CNT);
    unsigned* recs   = (unsigned*)((char*)d_ws + OFF_REC);

    hipLaunchKernelGGL(k_init, dim3((CNT_STRIDE * SUBS * NBINS + 255) / 256), dim3(256),
                       0, stream, vectors, vsum, counts);
    hipLaunchKernelGGL(k_transpose, dim3(3 * N_), dim3(256), 0, stream,
                       matrices, (__half2*)mt);
    hipLaunchKernelGGL(k_scatter, dim3(B_ / 256), dim3(256), 0, stream,
                       coords, counts, recs, mt, vsum, out);
    hipLaunchKernelGGL(k_gather, dim3(GATHER_BLOCKS), dim3(256), 0, stream,
                       coords, counts, recs, mt, vsum, out);
}